// Round 9
// baseline (6546.358 us; speedup 1.0000x reference)
//
#include <hip/hip_runtime.h>

typedef _Float16 h2 __attribute__((ext_vector_type(2)));
typedef _Float16 h8 __attribute__((ext_vector_type(8)));
typedef float f4 __attribute__((ext_vector_type(4)));

// Raw workgroup barrier: waits LDS ops only, leaves global loads/stores in flight.
#define LDS_BARRIER() asm volatile("s_waitcnt lgkmcnt(0)\n\ts_barrier" ::: "memory")

// ---------------- convert fp32 -> f16 ----------------
__global__ void cvt_f32_f16(const float* __restrict__ s, _Float16* __restrict__ d, int n) {
    int i = blockIdx.x * blockDim.x + threadIdx.x;
    if (i < n) d[i] = (_Float16)s[i];
}

// ---------------- combined GEMM bias: b_ih + b_hh for r,z cols; b_ih for n cols ----------------
__global__ void prep_bias(const float* __restrict__ bih, const float* __restrict__ bhh,
                          float* __restrict__ b2, int n) {
    int i = blockIdx.x * blockDim.x + threadIdx.x;
    if (i < n) {
        int c = i % 768;
        float v = bih[i];
        if (c < 512) v += bhh[i];
        b2[i] = v;
    }
}

// ---------------- x_proj GEMM: C[M][768] = A[M][256] * Bt[768][256]^T + bias ----------------
template<bool AF16>
__global__ __launch_bounds__(256, 2) void gemm_xproj(
    const void* __restrict__ Ap, const _Float16* __restrict__ Bt,
    const float* __restrict__ bias, float* __restrict__ C)
{
    __shared__ __align__(16) _Float16 As[128 * 40];
    __shared__ __align__(16) _Float16 Bs[128 * 40];
    const int tid = threadIdx.x;
    const size_t m0 = (size_t)blockIdx.x * 128;
    const int n0 = blockIdx.y * 128;
    const int lane = tid & 63, wave = tid >> 6;
    const int wm = wave >> 1, wn = wave & 1;
    const int r16 = lane & 15, kg = lane >> 4;
    f4 acc[4][4] = {};
    for (int k0 = 0; k0 < 256; k0 += 32) {
        if (k0) __syncthreads();
        #pragma unroll
        for (int u = 0; u < 2; ++u) {
            int c = tid + u * 256;
            int row = c >> 2, off = (c & 3) * 8;
            h8 av;
            if constexpr (AF16) {
                av = *(const h8*)((const _Float16*)Ap + (m0 + row) * 256 + k0 + off);
            } else {
                const float* ap = (const float*)Ap + (m0 + row) * 256 + k0 + off;
                f4 f0 = *(const f4*)ap, f1 = *(const f4*)(ap + 4);
                av[0]=(_Float16)f0[0]; av[1]=(_Float16)f0[1]; av[2]=(_Float16)f0[2]; av[3]=(_Float16)f0[3];
                av[4]=(_Float16)f1[0]; av[5]=(_Float16)f1[1]; av[6]=(_Float16)f1[2]; av[7]=(_Float16)f1[3];
            }
            *(h8*)&As[row * 40 + off] = av;
            h8 bv = *(const h8*)(Bt + (size_t)(n0 + row) * 256 + k0 + off);
            *(h8*)&Bs[row * 40 + off] = bv;
        }
        __syncthreads();
        h8 af[4], bf[4];
        #pragma unroll
        for (int mi = 0; mi < 4; ++mi) af[mi] = *(const h8*)&As[(wm*64 + mi*16 + r16) * 40 + kg * 8];
        #pragma unroll
        for (int ni = 0; ni < 4; ++ni) bf[ni] = *(const h8*)&Bs[(wn*64 + ni*16 + r16) * 40 + kg * 8];
        #pragma unroll
        for (int mi = 0; mi < 4; ++mi)
            #pragma unroll
            for (int ni = 0; ni < 4; ++ni)
                acc[mi][ni] = __builtin_amdgcn_mfma_f32_16x16x32_f16(af[mi], bf[ni], acc[mi][ni], 0, 0, 0);
    }
    #pragma unroll
    for (int mi = 0; mi < 4; ++mi)
        #pragma unroll
        for (int ni = 0; ni < 4; ++ni) {
            int col = n0 + wn*64 + ni*16 + r16;
            float bv = bias[col];
            #pragma unroll
            for (int r = 0; r < 4; ++r) {
                int row = wm*64 + mi*16 + kg*4 + r;
                C[(m0 + row) * 768 + col] = acc[mi][ni][r] + bv;
            }
        }
}

// ---------------- recurrent scan: 256 thr, 1 wave/SIMD, 512-reg budget, all resident ----------------
// 4 waves; wave w owns cols [64w, 64w+64). Bf = 3 gates x 4 nt x 8 kk = 384 regs; MFMA reads
// B in place (v or a regs). A (h) broadcast from LDS: all 16 A-rows identical -> D[ ][0] on
// every lane is the dot for col lane&15 -> uniform gate math, no shuffles.
template<bool OUTF32>
__global__
__attribute__((amdgpu_flat_work_group_size(256, 256), amdgpu_waves_per_eu(1, 1)))
void gru_scan_mfma(
    const float* __restrict__ xp,        // [B][T][768] fp32 (x_proj; b_ih + b_hh(r,z) folded)
    const _Float16* __restrict__ Whh,    // [768][256] f16
    const float* __restrict__ bhh,       // [768] (only n-part used)
    float* __restrict__ o32,             // layer 2 -> d_out
    _Float16* __restrict__ o16)          // layer 1 -> next GEMM input (f16)
{
    __shared__ __align__(16) _Float16 hh[2][256];
    const int b = blockIdx.x, tid = threadIdx.x;
    const int w = tid >> 6, lane = tid & 63;
    const int l15 = lane & 15, kg = lane >> 4;
    const int j0 = 64 * w;

    // one-time B-frag load: lane l holds W[g*256 + j0 + nt*16 + (l&15)][kk*32 + kg*8 .. +8]
    h8 Bf[3][4][8];
    #pragma unroll
    for (int g = 0; g < 3; ++g)
        #pragma unroll
        for (int nt = 0; nt < 4; ++nt) {
            const _Float16* rp = Whh + (size_t)(g * 256 + j0 + nt * 16 + l15) * 256 + kg * 8;
            #pragma unroll
            for (int kk = 0; kk < 8; ++kk)
                Bf[g][nt][kk] = *(const h8*)(rp + kk * 32);
        }

    float bn[4];
    #pragma unroll
    for (int nt = 0; nt < 4; ++nt) bn[nt] = bhh[512 + j0 + nt * 16 + l15];
    hh[0][tid] = (_Float16)1.0f;
    float hp[4] = {1.f, 1.f, 1.f, 1.f};
    const f4 Zc = {0.f, 0.f, 0.f, 0.f};          // persistent zero C-operand
    __syncthreads();

    const size_t xrow0 = (size_t)b * 2048;
    const int li = j0 + l15;                      // per-lane col base

    float cA[12], cB[12];
    {
        const float* xs = xp + xrow0 * 768;
        #pragma unroll
        for (int u = 0; u < 12; ++u) cA[u] = xs[li + (u >> 2) * 256 + (u & 3) * 16];
    }

    auto step = [&](int t, float (&cu)[12], float (&pf)[12],
                    const _Float16* hrd, _Float16* hwr) {
        // prefetch x_proj for t+1 (stays in flight across the LDS-only barrier)
        {
            const int tn = (t + 1 < 2048) ? t + 1 : 2047;
            const float* xs = xp + (xrow0 + tn) * 768;
            #pragma unroll
            for (int u = 0; u < 12; ++u) pf[u] = xs[li + (u >> 2) * 256 + (u & 3) * 16];
        }

        f4 D[12];
        #pragma unroll
        for (int kk = 0; kk < 8; ++kk) {
            h8 A = *(const h8*)(hrd + kk * 32 + kg * 8);     // broadcast read
            #pragma unroll
            for (int u = 0; u < 12; ++u) {
                if (kk == 0)
                    D[u] = __builtin_amdgcn_mfma_f32_16x16x32_f16(A, Bf[u >> 2][u & 3][0], Zc, 0, 0, 0);
                else
                    D[u] = __builtin_amdgcn_mfma_f32_16x16x32_f16(A, Bf[u >> 2][u & 3][kk], D[u], 0, 0, 0);
            }
        }

        float hn[4];
        #pragma unroll
        for (int nt = 0; nt < 4; ++nt) {
            float rg = 1.f / (1.f + __expf(-(cu[nt]     + D[nt][0])));
            float zg = 1.f / (1.f + __expf(-(cu[4 + nt] + D[4 + nt][0])));
            float na = cu[8 + nt] + rg * (D[8 + nt][0] + bn[nt]);
            float e  = __expf(-2.f * fabsf(na));
            float ng = copysignf((1.f - e) / (1.f + e), na);
            hn[nt] = (1.f - zg) * ng + zg * hp[nt];
            hp[nt] = hn[nt];
        }

        if (kg == 0) {
            #pragma unroll
            for (int nt = 0; nt < 4; ++nt) hwr[li + nt * 16] = (_Float16)hn[nt];
            const size_t ob = (xrow0 + t) * 256 + li;
            #pragma unroll
            for (int nt = 0; nt < 4; ++nt) {
                if constexpr (OUTF32) o32[ob + nt * 16] = hn[nt];
                else                  o16[ob + nt * 16] = (_Float16)hn[nt];
            }
        }
        LDS_BARRIER();
    };

    for (int t = 0; t < 2048; t += 2) {
        step(t,     cA, cB, hh[0], hh[1]);
        step(t + 1, cB, cA, hh[1], hh[0]);
    }
}

// ---------------- launch ----------------
extern "C" void kernel_launch(void* const* d_in, const int* in_sizes, int n_in,
                              void* d_out, int out_size, void* d_ws, size_t ws_size,
                              hipStream_t stream) {
    const float* x    = (const float*)d_in[0];
    const float* W_ih = (const float*)d_in[1];
    const float* W_hh = (const float*)d_in[2];
    const float* b_ih = (const float*)d_in[3];
    const float* b_hh = (const float*)d_in[4];
    float* out = (float*)d_out;

    char* ws = (char*)d_ws;
    float*     xproj = (float*)ws;                                   // 201,326,592 B
    _Float16*  Wih_h = (_Float16*)(ws + 201326592);
    _Float16*  Whh_h = (_Float16*)(ws + 201326592 + 786432);
    _Float16*  y1h   = (_Float16*)(ws + 201326592 + 2 * 786432);     // 33,554,432 B
    float*     bias2 = (float*)(ws + 201326592 + 2 * 786432 + 33554432);  // 6,144 B

    cvt_f32_f16<<<1536, 256, 0, stream>>>(W_ih, Wih_h, 393216);
    cvt_f32_f16<<<1536, 256, 0, stream>>>(W_hh, Whh_h, 393216);
    prep_bias<<<6, 256, 0, stream>>>(b_ih, b_hh, bias2, 1536);

    gemm_xproj<false><<<dim3(512, 6), 256, 0, stream>>>(x, Wih_h, bias2, xproj);
    gru_scan_mfma<false><<<32, 256, 0, stream>>>(xproj, Whh_h, b_hh, nullptr, y1h);

    gemm_xproj<true><<<dim3(512, 6), 256, 0, stream>>>(y1h, Wih_h + 196608, bias2 + 768, xproj);
    gru_scan_mfma<true><<<32, 256, 0, stream>>>(xproj, Whh_h + 196608, b_hh + 768, out, nullptr);
}